// Round 1
// baseline (204.019 us; speedup 1.0000x reference)
//
#include <hip/hip_runtime.h>
#include <math.h>

#define N1c 60000
#define N2c 15000
#define Kc  16
#define CINc 128
#define COUTc 64
#define Ec (N2c*Kc)
#define EPS 1e-5f

// order-preserving float<->uint encoding for atomicMax on floats
__device__ __forceinline__ unsigned enc_f32(float f) {
    unsigned u = __float_as_uint(f);
    return (u & 0x80000000u) ? ~u : (u | 0x80000000u);
}
__device__ __forceinline__ float dec_f32(unsigned u) {
    return (u & 0x80000000u) ? __uint_as_float(u & 0x7FFFFFFFu) : __uint_as_float(~u);
}

// K0: fold BN(cs) into per-channel scale/shift and pre-scale the 3 positional weight rows
__global__ void k0_prep(const float* __restrict__ cs_w1,
                        const float* __restrict__ g, const float* __restrict__ b,
                        const float* __restrict__ mn, const float* __restrict__ vr,
                        float* __restrict__ scale, float* __restrict__ shift,
                        float* __restrict__ wp0, float* __restrict__ wp1, float* __restrict__ wp2) {
    int c = threadIdx.x;
    if (c < CINc) {
        float s = rsqrtf(vr[c] + EPS) * g[c];
        scale[c] = s;
        shift[c] = b[c] - mn[c] * s;
        wp0[c] = cs_w1[0*CINc + c] * s;
        wp1[c] = cs_w1[1*CINc + c] * s;
        wp2[c] = cs_w1[2*CINc + c] * s;
    }
}

// K1: per p2-row m: base_bn[m,c] = bn-folded(x2[m] @ cs_w1[3:,c]) ; up_feat[m,c64] = relu(bn2(x2[m] @ lin2_w))
__global__ __launch_bounds__(192) void k1_base(
    const float* __restrict__ x2, const float* __restrict__ cs_w1,
    const float* __restrict__ lin2_w,
    const float* __restrict__ bn2_g, const float* __restrict__ bn2_b,
    const float* __restrict__ bn2_m, const float* __restrict__ bn2_v,
    const float* __restrict__ scale, const float* __restrict__ shift,
    float* __restrict__ base_bn, float* __restrict__ up_feat) {
    __shared__ float xs[CINc];
    int m = blockIdx.x;
    int t = threadIdx.x;
    if (t < CINc) xs[t] = x2[m*CINc + t];
    __syncthreads();
    if (t < CINc) {
        float acc = 0.f;
        #pragma unroll 8
        for (int k = 0; k < CINc; ++k)
            acc = fmaf(xs[k], cs_w1[(3+k)*CINc + t], acc);
        base_bn[m*CINc + t] = fmaf(acc, scale[t], shift[t]);
    } else {
        int c = t - CINc;  // 0..63
        float acc = 0.f;
        #pragma unroll 8
        for (int k = 0; k < CINc; ++k)
            acc = fmaf(xs[k], lin2_w[k*COUTc + c], acc);
        float h = (acc - bn2_m[c]) * rsqrtf(bn2_v[c] + EPS) * bn2_g[c] + bn2_b[c];
        up_feat[m*COUTc + c] = fmaxf(h, 0.f);
    }
}

// K2: per entry e=(m,k): logit; atomicMax segment max
__global__ __launch_bounds__(256) void k2_logits(
    const float* __restrict__ p1, const float* __restrict__ p2,
    const int* __restrict__ knn, const float* __restrict__ base_bn,
    const float* __restrict__ wp0, const float* __restrict__ wp1,
    const float* __restrict__ wp2, const float* __restrict__ w2,
    const float* __restrict__ b2,
    float* __restrict__ logits, unsigned* __restrict__ segmax) {
    int e = blockIdx.x * blockDim.x + threadIdx.x;
    if (e >= Ec) return;
    int m = e >> 4;
    int i = knn[e];
    float px = p1[i*3+0] - p2[m*3+0];
    float py = p1[i*3+1] - p2[m*3+1];
    float pz = p1[i*3+2] - p2[m*3+2];
    const float4* bb = reinterpret_cast<const float4*>(base_bn + m*CINc);
    const float4* a0 = reinterpret_cast<const float4*>(wp0);
    const float4* a1 = reinterpret_cast<const float4*>(wp1);
    const float4* a2 = reinterpret_cast<const float4*>(wp2);
    const float4* wv = reinterpret_cast<const float4*>(w2);
    float acc = 0.f;
    #pragma unroll 4
    for (int c = 0; c < CINc/4; ++c) {
        float4 b4 = bb[c], w04 = a0[c], w14 = a1[c], w24 = a2[c], wv4 = wv[c];
        float h;
        h = fmaf(px, w04.x, fmaf(py, w14.x, fmaf(pz, w24.x, b4.x))); h = fmaxf(h, 0.f); acc = fmaf(h, wv4.x, acc);
        h = fmaf(px, w04.y, fmaf(py, w14.y, fmaf(pz, w24.y, b4.y))); h = fmaxf(h, 0.f); acc = fmaf(h, wv4.y, acc);
        h = fmaf(px, w04.z, fmaf(py, w14.z, fmaf(pz, w24.z, b4.z))); h = fmaxf(h, 0.f); acc = fmaf(h, wv4.z, acc);
        h = fmaf(px, w04.w, fmaf(py, w14.w, fmaf(pz, w24.w, b4.w))); h = fmaxf(h, 0.f); acc = fmaf(h, wv4.w, acc);
    }
    float lg = acc + b2[0];
    logits[e] = lg;
    atomicMax(segmax + i, enc_f32(lg));
}

// K3: ex = exp(logit - segmax); atomicAdd denom
__global__ __launch_bounds__(256) void k3_exp(
    const int* __restrict__ knn, const float* __restrict__ logits,
    const unsigned* __restrict__ segmax,
    float* __restrict__ exv, float* __restrict__ denom) {
    int e = blockIdx.x * blockDim.x + threadIdx.x;
    if (e >= Ec) return;
    int i = knn[e];
    float mx = dec_f32(segmax[i]);
    float ev = expf(logits[e] - mx);
    exv[e] = ev;
    atomicAdd(denom + i, ev);
}

// K5: d_out = relu(bn1(x1 @ lin1_w))   (runs BEFORE scatter)
__global__ __launch_bounds__(256) void k5_ybase(
    const float* __restrict__ x1, const float* __restrict__ lin1_w,
    const float* __restrict__ g, const float* __restrict__ b,
    const float* __restrict__ mn, const float* __restrict__ vr,
    float* __restrict__ out) {
    int tid = blockIdx.x * blockDim.x + threadIdx.x;
    if (tid >= N1c*COUTc) return;
    int row = tid >> 6, c = tid & 63;
    const float* xr = x1 + row*COUTc;
    float acc = 0.f;
    #pragma unroll 8
    for (int k = 0; k < COUTc; ++k)
        acc = fmaf(xr[k], lin1_w[k*COUTc + c], acc);
    float h = (acc - mn[c]) * rsqrtf(vr[c] + EPS) * g[c] + b[c];
    out[tid] = fmaxf(h, 0.f);
}

// K4: scatter prob * up_feat into out; one wave (64 lanes) per entry, lane = channel
__global__ __launch_bounds__(256) void k4_scatter(
    const int* __restrict__ knn, const float* __restrict__ exv,
    const float* __restrict__ denom, const float* __restrict__ up_feat,
    float* __restrict__ out) {
    int tid = blockIdx.x * blockDim.x + threadIdx.x;
    if (tid >= Ec*COUTc) return;
    int e = tid >> 6;
    int c = tid & 63;
    int i = knn[e];
    int m = e >> 4;
    float prob = exv[e] / denom[i];
    atomicAdd(out + i*COUTc + c, prob * up_feat[m*COUTc + c]);
}

extern "C" void kernel_launch(void* const* d_in, const int* in_sizes, int n_in,
                              void* d_out, int out_size, void* d_ws, size_t ws_size,
                              hipStream_t stream) {
    const float* p1     = (const float*)d_in[0];
    const float* x1     = (const float*)d_in[1];
    const float* p2     = (const float*)d_in[2];
    const float* x2     = (const float*)d_in[3];
    const int*   knn    = (const int*)d_in[4];
    const float* lin1_w = (const float*)d_in[5];
    const float* bn1_g  = (const float*)d_in[6];
    const float* bn1_b  = (const float*)d_in[7];
    const float* bn1_m  = (const float*)d_in[8];
    const float* bn1_v  = (const float*)d_in[9];
    const float* lin2_w = (const float*)d_in[10];
    const float* bn2_g  = (const float*)d_in[11];
    const float* bn2_b  = (const float*)d_in[12];
    const float* bn2_m  = (const float*)d_in[13];
    const float* bn2_v  = (const float*)d_in[14];
    const float* cs_w1  = (const float*)d_in[15];
    const float* bncs_g = (const float*)d_in[16];
    const float* bncs_b = (const float*)d_in[17];
    const float* bncs_m = (const float*)d_in[18];
    const float* bncs_v = (const float*)d_in[19];
    const float* cs_w2  = (const float*)d_in[20];
    const float* cs_b2  = (const float*)d_in[21];

    char* w = (char*)d_ws;
    float* scale = (float*)w;            // 128 f
    float* shift = scale + CINc;         // 128 f
    float* wp0   = shift + CINc;         // 128 f
    float* wp1   = wp0 + CINc;           // 128 f
    float* wp2   = wp1 + CINc;           // 128 f
    w += 4096;
    float* base_bn = (float*)w;  w += (size_t)N2c*CINc*4;   // 7.68 MB
    float* up_feat = (float*)w;  w += (size_t)N2c*COUTc*4;  // 3.84 MB
    float* logits  = (float*)w;  w += (size_t)Ec*4;         // 0.96 MB
    float* exv     = (float*)w;  w += (size_t)Ec*4;         // 0.96 MB
    unsigned* segmax = (unsigned*)w; w += (size_t)N1c*4;    // 0.24 MB
    float* denom   = (float*)w;  w += (size_t)N1c*4;        // 0.24 MB

    hipMemsetAsync(segmax, 0, N1c*sizeof(unsigned), stream);
    hipMemsetAsync(denom,  0, N1c*sizeof(float),    stream);

    k0_prep<<<1, CINc, 0, stream>>>(cs_w1, bncs_g, bncs_b, bncs_m, bncs_v,
                                    scale, shift, wp0, wp1, wp2);
    k1_base<<<N2c, 192, 0, stream>>>(x2, cs_w1, lin2_w, bn2_g, bn2_b, bn2_m, bn2_v,
                                     scale, shift, base_bn, up_feat);
    k2_logits<<<(Ec+255)/256, 256, 0, stream>>>(p1, p2, knn, base_bn,
                                                wp0, wp1, wp2, cs_w2, cs_b2,
                                                logits, segmax);
    k3_exp<<<(Ec+255)/256, 256, 0, stream>>>(knn, logits, segmax, exv, denom);
    k5_ybase<<<(N1c*COUTc+255)/256, 256, 0, stream>>>(x1, lin1_w, bn1_g, bn1_b, bn1_m, bn1_v,
                                                      (float*)d_out);
    k4_scatter<<<(Ec*COUTc+255)/256, 256, 0, stream>>>(knn, exv, denom, up_feat,
                                                       (float*)d_out);
}

// Round 2
// 153.816 us; speedup vs baseline: 1.3264x; 1.3264x over previous
//
#include <hip/hip_runtime.h>
#include <math.h>

#define N1c 60000
#define N2c 15000
#define Kc  16
#define CINc 128
#define COUTc 64
#define Ec (N2c*Kc)
#define EPS 1e-5f

// order-preserving float<->uint encoding for atomicMax on floats
__device__ __forceinline__ unsigned enc_f32(float f) {
    unsigned u = __float_as_uint(f);
    return (u & 0x80000000u) ? ~u : (u | 0x80000000u);
}
__device__ __forceinline__ float dec_f32(unsigned u) {
    return (u & 0x80000000u) ? __uint_as_float(u & 0x7FFFFFFFu) : __uint_as_float(~u);
}

// K0: fold BN(cs) into per-channel scale/shift and pre-scale the 3 positional weight rows
__global__ void k0_prep(const float* __restrict__ cs_w1,
                        const float* __restrict__ g, const float* __restrict__ b,
                        const float* __restrict__ mn, const float* __restrict__ vr,
                        float* __restrict__ scale, float* __restrict__ shift,
                        float* __restrict__ wp0, float* __restrict__ wp1, float* __restrict__ wp2) {
    int c = threadIdx.x;
    if (c < CINc) {
        float s = rsqrtf(vr[c] + EPS) * g[c];
        scale[c] = s;
        shift[c] = b[c] - mn[c] * s;
        wp0[c] = cs_w1[0*CINc + c] * s;
        wp1[c] = cs_w1[1*CINc + c] * s;
        wp2[c] = cs_w1[2*CINc + c] * s;
    }
}

// K1: per p2-row m: base_bn[m,c] = bn-folded(x2[m] @ cs_w1[3:,c]) ;
//     up_feat[m,c64] = relu(bn2(x2[m] @ lin2_w))
// 192 threads = 192 output columns (128 base + 64 up). 20 rows per block.
// x2 tile staged in LDS, read broadcast; each weight load feeds 20 FMAs.
#define R1 20
__global__ __launch_bounds__(192) void k1_base(
    const float* __restrict__ x2, const float* __restrict__ cs_w1,
    const float* __restrict__ lin2_w,
    const float* __restrict__ bn2_g, const float* __restrict__ bn2_b,
    const float* __restrict__ bn2_m, const float* __restrict__ bn2_v,
    const float* __restrict__ scale, const float* __restrict__ shift,
    float* __restrict__ base_bn, float* __restrict__ up_feat) {
    __shared__ float4 xs4[R1 * (CINc/4)];   // 20 rows x 128 f = 10 KB
    int c = threadIdx.x;
    int m0 = blockIdx.x * R1;
    const float4* src4 = reinterpret_cast<const float4*>(x2 + (size_t)m0 * CINc);
    for (int t = c; t < R1 * (CINc/4); t += 192) xs4[t] = src4[t];
    __syncthreads();

    float acc[R1];
    #pragma unroll
    for (int r = 0; r < R1; ++r) acc[r] = 0.f;

    if (c < CINc) {
        for (int kt = 0; kt < CINc/4; ++kt) {
            float w0 = cs_w1[(3 + kt*4 + 0)*CINc + c];
            float w1 = cs_w1[(3 + kt*4 + 1)*CINc + c];
            float w2 = cs_w1[(3 + kt*4 + 2)*CINc + c];
            float w3 = cs_w1[(3 + kt*4 + 3)*CINc + c];
            #pragma unroll
            for (int r = 0; r < R1; ++r) {
                float4 xv = xs4[r*(CINc/4) + kt];
                acc[r] = fmaf(xv.x, w0, acc[r]);
                acc[r] = fmaf(xv.y, w1, acc[r]);
                acc[r] = fmaf(xv.z, w2, acc[r]);
                acc[r] = fmaf(xv.w, w3, acc[r]);
            }
        }
        float s = scale[c], sh = shift[c];
        #pragma unroll
        for (int r = 0; r < R1; ++r)
            base_bn[(size_t)(m0 + r)*CINc + c] = fmaf(acc[r], s, sh);
    } else {
        int cc = c - CINc;  // 0..63
        for (int kt = 0; kt < CINc/4; ++kt) {
            float w0 = lin2_w[(kt*4 + 0)*COUTc + cc];
            float w1 = lin2_w[(kt*4 + 1)*COUTc + cc];
            float w2 = lin2_w[(kt*4 + 2)*COUTc + cc];
            float w3 = lin2_w[(kt*4 + 3)*COUTc + cc];
            #pragma unroll
            for (int r = 0; r < R1; ++r) {
                float4 xv = xs4[r*(CINc/4) + kt];
                acc[r] = fmaf(xv.x, w0, acc[r]);
                acc[r] = fmaf(xv.y, w1, acc[r]);
                acc[r] = fmaf(xv.z, w2, acc[r]);
                acc[r] = fmaf(xv.w, w3, acc[r]);
            }
        }
        float s = rsqrtf(bn2_v[cc] + EPS) * bn2_g[cc];
        float sh = bn2_b[cc] - bn2_m[cc] * s;
        #pragma unroll
        for (int r = 0; r < R1; ++r)
            up_feat[(size_t)(m0 + r)*COUTc + cc] = fmaxf(fmaf(acc[r], s, sh), 0.f);
    }
}

// K2: per entry e=(m,k): logit; atomicMax segment max
__global__ __launch_bounds__(256) void k2_logits(
    const float* __restrict__ p1, const float* __restrict__ p2,
    const int* __restrict__ knn, const float* __restrict__ base_bn,
    const float* __restrict__ wp0, const float* __restrict__ wp1,
    const float* __restrict__ wp2, const float* __restrict__ w2,
    const float* __restrict__ b2,
    float* __restrict__ logits, unsigned* __restrict__ segmax) {
    int e = blockIdx.x * blockDim.x + threadIdx.x;
    if (e >= Ec) return;
    int m = e >> 4;
    int i = knn[e];
    float px = p1[i*3+0] - p2[m*3+0];
    float py = p1[i*3+1] - p2[m*3+1];
    float pz = p1[i*3+2] - p2[m*3+2];
    const float4* bb = reinterpret_cast<const float4*>(base_bn + (size_t)m*CINc);
    const float4* a0 = reinterpret_cast<const float4*>(wp0);
    const float4* a1 = reinterpret_cast<const float4*>(wp1);
    const float4* a2 = reinterpret_cast<const float4*>(wp2);
    const float4* wv = reinterpret_cast<const float4*>(w2);
    float acc = 0.f;
    #pragma unroll 4
    for (int c = 0; c < CINc/4; ++c) {
        float4 b4 = bb[c], w04 = a0[c], w14 = a1[c], w24 = a2[c], wv4 = wv[c];
        float h;
        h = fmaf(px, w04.x, fmaf(py, w14.x, fmaf(pz, w24.x, b4.x))); h = fmaxf(h, 0.f); acc = fmaf(h, wv4.x, acc);
        h = fmaf(px, w04.y, fmaf(py, w14.y, fmaf(pz, w24.y, b4.y))); h = fmaxf(h, 0.f); acc = fmaf(h, wv4.y, acc);
        h = fmaf(px, w04.z, fmaf(py, w14.z, fmaf(pz, w24.z, b4.z))); h = fmaxf(h, 0.f); acc = fmaf(h, wv4.z, acc);
        h = fmaf(px, w04.w, fmaf(py, w14.w, fmaf(pz, w24.w, b4.w))); h = fmaxf(h, 0.f); acc = fmaf(h, wv4.w, acc);
    }
    float lg = acc + b2[0];
    logits[e] = lg;
    atomicMax(segmax + i, enc_f32(lg));
}

// K3: ex = exp(logit - segmax); atomicAdd denom
__global__ __launch_bounds__(256) void k3_exp(
    const int* __restrict__ knn, const float* __restrict__ logits,
    const unsigned* __restrict__ segmax,
    float* __restrict__ exv, float* __restrict__ denom) {
    int e = blockIdx.x * blockDim.x + threadIdx.x;
    if (e >= Ec) return;
    int i = knn[e];
    float mx = dec_f32(segmax[i]);
    float ev = expf(logits[e] - mx);
    exv[e] = ev;
    atomicAdd(denom + i, ev);
}

// K5: d_out = relu(bn1(x1 @ lin1_w))   (runs BEFORE scatter)
// lane = output channel; weight column preloaded in 64 VGPRs; 8 rows per wave.
__global__ __launch_bounds__(256) void k5_ybase(
    const float* __restrict__ x1, const float* __restrict__ lin1_w,
    const float* __restrict__ g, const float* __restrict__ b,
    const float* __restrict__ mn, const float* __restrict__ vr,
    float* __restrict__ out) {
    int c  = threadIdx.x & 63;
    int wv = threadIdx.x >> 6;
    float wcol[COUTc];
    #pragma unroll
    for (int k = 0; k < COUTc; ++k) wcol[k] = lin1_w[k*COUTc + c];
    float s  = rsqrtf(vr[c] + EPS) * g[c];
    float sh = b[c] - mn[c] * s;
    int row0 = (blockIdx.x * 4 + wv) * 8;            // 1875 blocks * 32 rows = 60000 exact
    int rbase = __builtin_amdgcn_readfirstlane(row0);
    #pragma unroll
    for (int r = 0; r < 8; ++r) {
        int row = rbase + r;
        const float4* xr = reinterpret_cast<const float4*>(x1 + (size_t)row * COUTc);
        float acc = 0.f;
        #pragma unroll
        for (int k4 = 0; k4 < COUTc/4; ++k4) {
            float4 xv = xr[k4];
            acc = fmaf(xv.x, wcol[k4*4+0], acc);
            acc = fmaf(xv.y, wcol[k4*4+1], acc);
            acc = fmaf(xv.z, wcol[k4*4+2], acc);
            acc = fmaf(xv.w, wcol[k4*4+3], acc);
        }
        out[(size_t)row*COUTc + c] = fmaxf(fmaf(acc, s, sh), 0.f);
    }
}

// K4: scatter prob * up_feat into out; 64 lanes per entry, lane = channel
__global__ __launch_bounds__(256) void k4_scatter(
    const int* __restrict__ knn, const float* __restrict__ exv,
    const float* __restrict__ denom, const float* __restrict__ up_feat,
    float* __restrict__ out) {
    int tid = blockIdx.x * blockDim.x + threadIdx.x;
    if (tid >= Ec*COUTc) return;
    int e = tid >> 6;
    int c = tid & 63;
    int i = knn[e];
    int m = e >> 4;
    float prob = exv[e] / denom[i];
    atomicAdd(out + (size_t)i*COUTc + c, prob * up_feat[(size_t)m*COUTc + c]);
}

extern "C" void kernel_launch(void* const* d_in, const int* in_sizes, int n_in,
                              void* d_out, int out_size, void* d_ws, size_t ws_size,
                              hipStream_t stream) {
    const float* p1     = (const float*)d_in[0];
    const float* x1     = (const float*)d_in[1];
    const float* p2     = (const float*)d_in[2];
    const float* x2     = (const float*)d_in[3];
    const int*   knn    = (const int*)d_in[4];
    const float* lin1_w = (const float*)d_in[5];
    const float* bn1_g  = (const float*)d_in[6];
    const float* bn1_b  = (const float*)d_in[7];
    const float* bn1_m  = (const float*)d_in[8];
    const float* bn1_v  = (const float*)d_in[9];
    const float* lin2_w = (const float*)d_in[10];
    const float* bn2_g  = (const float*)d_in[11];
    const float* bn2_b  = (const float*)d_in[12];
    const float* bn2_m  = (const float*)d_in[13];
    const float* bn2_v  = (const float*)d_in[14];
    const float* cs_w1  = (const float*)d_in[15];
    const float* bncs_g = (const float*)d_in[16];
    const float* bncs_b = (const float*)d_in[17];
    const float* bncs_m = (const float*)d_in[18];
    const float* bncs_v = (const float*)d_in[19];
    const float* cs_w2  = (const float*)d_in[20];
    const float* cs_b2  = (const float*)d_in[21];

    char* w = (char*)d_ws;
    float* scale = (float*)w;            // 128 f
    float* shift = scale + CINc;         // 128 f
    float* wp0   = shift + CINc;         // 128 f
    float* wp1   = wp0 + CINc;           // 128 f
    float* wp2   = wp1 + CINc;           // 128 f
    w += 4096;
    float* base_bn = (float*)w;  w += (size_t)N2c*CINc*4;   // 7.68 MB
    float* up_feat = (float*)w;  w += (size_t)N2c*COUTc*4;  // 3.84 MB
    float* logits  = (float*)w;  w += (size_t)Ec*4;         // 0.96 MB
    float* exv     = (float*)w;  w += (size_t)Ec*4;         // 0.96 MB
    unsigned* segmax = (unsigned*)w; w += (size_t)N1c*4;    // 0.24 MB
    float* denom   = (float*)w;  w += (size_t)N1c*4;        // 0.24 MB

    hipMemsetAsync(segmax, 0, N1c*sizeof(unsigned), stream);
    hipMemsetAsync(denom,  0, N1c*sizeof(float),    stream);

    k0_prep<<<1, CINc, 0, stream>>>(cs_w1, bncs_g, bncs_b, bncs_m, bncs_v,
                                    scale, shift, wp0, wp1, wp2);
    k1_base<<<N2c/R1, 192, 0, stream>>>(x2, cs_w1, lin2_w, bn2_g, bn2_b, bn2_m, bn2_v,
                                        scale, shift, base_bn, up_feat);
    k2_logits<<<(Ec+255)/256, 256, 0, stream>>>(p1, p2, knn, base_bn,
                                                wp0, wp1, wp2, cs_w2, cs_b2,
                                                logits, segmax);
    k3_exp<<<(Ec+255)/256, 256, 0, stream>>>(knn, logits, segmax, exv, denom);
    k5_ybase<<<N1c/32, 256, 0, stream>>>(x1, lin1_w, bn1_g, bn1_b, bn1_m, bn1_v,
                                         (float*)d_out);
    k4_scatter<<<((size_t)Ec*COUTc+255)/256, 256, 0, stream>>>(knn, exv, denom, up_feat,
                                                               (float*)d_out);
}